// Round 1
// baseline (2788.774 us; speedup 1.0000x reference)
//
#include <hip/hip_runtime.h>
#include <hip/hip_bf16.h>

// Problem constants
#define N_CELLS   3872
#define NCLS      80
#define NFLAT     309760        // 3872*80
#define FH        128
#define FW        192
#define HW        24576         // 128*192
#define WORDS     384           // HW/64
#define PRE       500
#define OH        512
#define OW        768
#define OPIX      393216        // 512*768
#define MAXI      100
#define NBUCKET   16384
#define COLCAP    4096

// Workspace byte offsets (all 8B aligned)
#define OFF_HIST      0          // u32[16384]
#define OFF_CNT       65536      // u32[16]   [0]=collect count, [1]=bucket B
#define OFF_KEYBUF    65600      // u64[4096]
#define OFF_EGIDX     98368      // i32[512]
#define OFF_ELABEL    100416     // i32[512]
#define OFF_ECOUNT    102464     // i32[512]
#define OFF_TKSCORE   104512     // f32[512]
#define OFF_ESCORE1   106560     // f64[512]
#define OFF_ORDER1    110656     // i32[512]
#define OFF_SCORES    112704     // f64[512]  sorted-1 scores
#define OFF_COMP      116800     // f32[512]
#define OFF_ECI       118848     // f64[512]  exp(comp^2/2)
#define OFF_NS        122944     // f64[512]  post-NMS scores (sorted-1 space)
#define OFF_FINALE    127040     // i32[128]
#define OFF_BOXESI    127552     // i32[400]
#define OFF_PACKED    129152     // u64[500*384]
#define OFF_DMAT      1665152    // f32[500*500]
// total ~2.67 MB

__device__ __forceinline__ float stride_of(int g) {
    return (g < 2896) ? 8.0f : (g < 3472) ? 16.0f : 32.0f;
}

__device__ __forceinline__ int bucket_of(float v) {
    int b = (int)((v - 0.1f) * (16384.0f / 0.9f));
    return min(max(b, 0), NBUCKET - 1);
}

// ---------------- init ----------------
__global__ void k_init(unsigned* hist, unsigned* counters, int* boxes) {
    int i = blockIdx.x * blockDim.x + threadIdx.x;
    if (i < NBUCKET) hist[i] = 0u;
    if (i < 16) counters[i] = 0u;
    if (i < MAXI) {
        boxes[4*i+0] = OW;   // xmin sentinel
        boxes[4*i+1] = OH;   // ymin sentinel
        boxes[4*i+2] = 0;    // xmax sentinel
        boxes[4*i+3] = 0;    // ymax sentinel
    }
}

// ---------------- histogram of cate scores > 0.1 ----------------
__global__ void k_hist(const float* __restrict__ cate, unsigned* __restrict__ hist) {
    int i = blockIdx.x * blockDim.x + threadIdx.x;
    if (i >= NFLAT) return;
    float v = cate[i];
    if (v > 0.1f) atomicAdd(&hist[bucket_of(v)], 1u);
}

// ---------------- find bucket threshold B (top-500 live in buckets >= B) ----------------
__global__ __launch_bounds__(1024) void k_findB(const unsigned* __restrict__ hist, unsigned* counters) {
    __shared__ unsigned part[1024];
    int t = threadIdx.x;
    unsigned s = 0;
    for (int k = 0; k < 16; k++) s += hist[t * 16 + k];
    part[t] = s;
    __syncthreads();
    if (t == 0) {
        unsigned cum = 0;
        int B = 0;
        for (int c = 1023; c >= 0; c--) {
            if (cum + part[c] >= (unsigned)PRE) {
                unsigned cum2 = cum;
                int b = c * 16 + 15;
                for (; b >= c * 16; b--) {
                    cum2 += hist[b];
                    if (cum2 >= (unsigned)PRE) break;
                }
                B = (b < c * 16) ? c * 16 : b;
                counters[1] = (unsigned)B;
                return;
            }
            cum += part[c];
        }
        counters[1] = 0u;  // fewer than 500 candidates total
    }
}

// ---------------- collect candidates in buckets >= B ----------------
__global__ void k_collect(const float* __restrict__ cate, unsigned* counters,
                          unsigned long long* __restrict__ keybuf) {
    int i = blockIdx.x * blockDim.x + threadIdx.x;
    if (i >= NFLAT) return;
    float v = cate[i];
    if (v > 0.1f) {
        if (bucket_of(v) >= (int)counters[1]) {
            unsigned pos = atomicAdd(&counters[0], 1u);
            if (pos < COLCAP) {
                unsigned fb = __float_as_uint(v);
                keybuf[pos] = ((unsigned long long)fb << 32) | (unsigned long long)(0xFFFFFFFFu - (unsigned)i);
            }
        }
    }
}

// ---------------- sort collected (<=4096) desc, emit top-500 ----------------
__global__ __launch_bounds__(1024) void k_sort_collect(const unsigned long long* __restrict__ keybuf,
                                                       const unsigned* counters,
                                                       int* e_gidx, int* e_label, float* tk_score) {
    __shared__ unsigned long long k[COLCAP];
    int t = threadIdx.x;
    unsigned cnt = counters[0];
    if (cnt > COLCAP) cnt = COLCAP;
    for (int i = t; i < COLCAP; i += 1024) k[i] = (i < (int)cnt) ? keybuf[i] : 0ull;
    __syncthreads();
    for (int sz = 2; sz <= COLCAP; sz <<= 1) {
        for (int j = sz >> 1; j > 0; j >>= 1) {
            for (int i = t; i < COLCAP; i += 1024) {
                int ixj = i ^ j;
                if (ixj > i) {
                    bool up = ((i & sz) == 0);
                    unsigned long long a = k[i], b = k[ixj];
                    bool sw = up ? (a < b) : (a > b);   // descending
                    if (sw) { k[i] = b; k[ixj] = a; }
                }
            }
            __syncthreads();
        }
    }
    if (t < PRE) {
        unsigned long long key = k[t];
        if (key == 0ull) {  // defensive: fewer than 500 candidates
            e_gidx[t] = 0; e_label[t] = 0; tk_score[t] = -1.0f;
        } else {
            unsigned idx = 0xFFFFFFFFu - (unsigned)(key & 0xFFFFFFFFull);
            e_gidx[t] = (int)(idx / NCLS);
            e_label[t] = (int)(idx % NCLS);
            tk_score[t] = __uint_as_float((unsigned)(key >> 32));
        }
    }
}

// ---------------- per-candidate mask stats + bit-pack ----------------
__global__ __launch_bounds__(256) void k_maskstats(const float* __restrict__ seg,
                                                   const int* __restrict__ e_gidx,
                                                   const float* __restrict__ tk_score,
                                                   unsigned long long* __restrict__ packed,
                                                   int* __restrict__ e_count,
                                                   double* __restrict__ e_score1) {
    int e = blockIdx.x;
    const float* row = seg + (size_t)e_gidx[e] * HW;
    int t = threadIdx.x;
    int lane = t & 63;
    int wv = t >> 6;
    double lsum = 0.0;
    int lcnt = 0;
    for (int p = t; p < HW; p += 256) {
        float v = row[p];
        bool m = v > 0.5f;
        unsigned long long bal = __ballot(m);
        if (lane == 0) packed[(size_t)e * WORDS + (p >> 6)] = bal;
        if (m) { lsum += (double)v; lcnt++; }
    }
    for (int off = 32; off > 0; off >>= 1) {
        lsum += __shfl_down(lsum, off);
        lcnt += __shfl_down(lcnt, off);
    }
    __shared__ double ssum[4];
    __shared__ int scnt[4];
    if (lane == 0) { ssum[wv] = lsum; scnt[wv] = lcnt; }
    __syncthreads();
    if (t == 0) {
        double sum = ssum[0] + ssum[1] + ssum[2] + ssum[3];
        int cnt = scnt[0] + scnt[1] + scnt[2] + scnt[3];
        double segsc = sum / (double)max(cnt, 1);
        float sc = tk_score[e];
        bool keep = (sc > 0.1f) && ((float)cnt > stride_of(e_gidx[e]));
        e_count[e] = cnt;
        e_score1[e] = keep ? ((double)sc * segsc) : 0.0;
    }
}

// ---------------- stable descending sort of 500 doubles, emit permutation ----------------
__device__ __forceinline__ bool before_key(unsigned long long as, int ai,
                                           unsigned long long bs, int bi) {
    return (as > bs) || (as == bs && ai < bi);
}

__global__ __launch_bounds__(512) void k_sort1(const double* __restrict__ e_score1,
                                               int* __restrict__ order1,
                                               double* __restrict__ score_s) {
    __shared__ unsigned long long sb[512];
    __shared__ int si[512];
    int t = threadIdx.x;
    sb[t] = (t < PRE) ? (unsigned long long)__double_as_longlong(e_score1[t]) : 0ull;
    si[t] = t;
    __syncthreads();
    for (int sz = 2; sz <= 512; sz <<= 1) {
        for (int j = sz >> 1; j > 0; j >>= 1) {
            int ixj = t ^ j;
            if (ixj > t) {
                unsigned long long as = sb[t], bs = sb[ixj];
                int ai = si[t], bi = si[ixj];
                bool up = ((t & sz) == 0);
                bool aB = before_key(as, ai, bs, bi);
                bool sw = up ? (!aB) : aB;
                if (sw) { sb[t] = bs; sb[ixj] = as; si[t] = bi; si[ixj] = ai; }
            }
            __syncthreads();
        }
    }
    if (t < PRE) {
        order1[t] = si[t];
        score_s[t] = __longlong_as_double((long long)sb[t]);
    }
}

// ---------------- decay_iou matrix (upper triangle, same-label) ----------------
__global__ __launch_bounds__(256) void k_dmat(const unsigned long long* __restrict__ packed,
                                              const int* __restrict__ order1,
                                              const int* __restrict__ e_count,
                                              const int* __restrict__ e_label,
                                              float* __restrict__ dmat) {
    int bi = blockIdx.x, bj = blockIdx.y;
    int r = threadIdx.x >> 4, c = threadIdx.x & 15;
    int i = bi * 16 + r, j = bj * 16 + c;
    if (bi > bj) {  // whole tile is lower triangle -> zeros
        if (i < PRE && j < PRE) dmat[i * PRE + j] = 0.0f;
        return;
    }
    __shared__ unsigned long long A[16][65];
    __shared__ unsigned long long B[16][65];
    int oi = (i < PRE) ? order1[i] : -1;
    int oj = (j < PRE) ? order1[j] : -1;
    long long inter = 0;
    for (int ch = 0; ch < 6; ch++) {
        for (int l = threadIdx.x; l < 1024; l += 256) {
            int rr = l >> 6, ww = l & 63;
            int ii = bi * 16 + rr;
            int o = (ii < PRE) ? order1[ii] : -1;
            A[rr][ww] = (o >= 0) ? packed[(size_t)o * WORDS + ch * 64 + ww] : 0ull;
            int jj = bj * 16 + rr;
            int o2 = (jj < PRE) ? order1[jj] : -1;
            B[rr][ww] = (o2 >= 0) ? packed[(size_t)o2 * WORDS + ch * 64 + ww] : 0ull;
        }
        __syncthreads();
        #pragma unroll
        for (int w = 0; w < 64; w++) inter += __popcll(A[r][w] & B[c][w]);
        __syncthreads();
    }
    if (i < PRE && j < PRE) {
        float d = 0.0f;
        if (i < j && e_label[oi] == e_label[oj]) {
            double un = (double)(e_count[oi] + e_count[oj]) - (double)inter;
            double iou = (double)inter / fmax(un, 1e-6);
            d = (float)iou;
        }
        dmat[i * PRE + j] = d;
    }
}

// ---------------- compensate (column max) + exp(comp^2/2) ----------------
__global__ __launch_bounds__(512) void k_comp(const float* __restrict__ dmat,
                                              float* __restrict__ comp,
                                              double* __restrict__ eci) {
    int t = threadIdx.x;
    if (t < PRE) {
        float m = 0.0f;
        for (int i = 0; i < PRE; i++) m = fmaxf(m, dmat[i * PRE + t]);
        comp[t] = m;
        eci[t] = exp((double)m * (double)m * 0.5);
    }
}

// ---------------- coef (column min of decay) + score update ----------------
__global__ __launch_bounds__(512) void k_coef(const float* __restrict__ dmat,
                                              const float* __restrict__ comp,
                                              const double* __restrict__ eci,
                                              const double* __restrict__ score_s,
                                              double* __restrict__ ns) {
    int t = threadIdx.x;
    if (t < PRE) {
        double m = 1e300;
        for (int i = 0; i < PRE; i++) {
            float d = dmat[i * PRE + t];
            double v;
            if (d != 0.0f) {
                double dd = (double)d, cc = (double)comp[i];
                v = exp(-(dd * dd - cc * cc) * 0.5);
            } else {
                v = eci[i];
            }
            m = fmin(m, v);
        }
        double s = score_s[t] * m;
        if (s < 0.05) s = 0.0;
        ns[t] = s;
    }
}

// ---------------- final stable sort, emit scores/labels/final_e ----------------
__global__ __launch_bounds__(512) void k_sort2(const double* __restrict__ ns,
                                               const int* __restrict__ order1,
                                               const int* __restrict__ e_label,
                                               float* __restrict__ out,
                                               int* __restrict__ final_e) {
    __shared__ unsigned long long sb[512];
    __shared__ int si[512];
    int t = threadIdx.x;
    sb[t] = (t < PRE) ? (unsigned long long)__double_as_longlong(ns[t]) : 0ull;
    si[t] = t;
    __syncthreads();
    for (int sz = 2; sz <= 512; sz <<= 1) {
        for (int j = sz >> 1; j > 0; j >>= 1) {
            int ixj = t ^ j;
            if (ixj > t) {
                unsigned long long as = sb[t], bs = sb[ixj];
                int ai = si[t], bi = si[ixj];
                bool up = ((t & sz) == 0);
                bool aB = before_key(as, ai, bs, bi);
                bool sw = up ? (!aB) : aB;
                if (sw) { sb[t] = bs; sb[ixj] = as; si[t] = bi; si[ixj] = ai; }
            }
            __syncthreads();
        }
    }
    if (t < MAXI) {
        double s = __longlong_as_double((long long)sb[t]);
        int p = si[t];
        int e = order1[p];
        out[t] = (float)s;
        out[MAXI + t] = (float)e_label[e];
        final_e[t] = e;
    }
}

// ---------------- upsample 4x bilinear + threshold + bbox ----------------
__global__ __launch_bounds__(256) void k_upsample(const float* __restrict__ seg,
                                                  const int* __restrict__ final_e,
                                                  const int* __restrict__ e_gidx,
                                                  float* __restrict__ out,
                                                  int* __restrict__ boxes_i) {
    int f = blockIdx.y;
    int e = final_e[f];
    int g = e_gidx[e];
    const float* row = seg + (size_t)g * HW;
    int pix = blockIdx.x * 256 + threadIdx.x;  // block covers 256 consecutive x in one row
    int oy = pix / OW, ox = pix - oy * OW;
    float iny = (float)oy * 0.25f - 0.375f;
    float inx = (float)ox * 0.25f - 0.375f;
    int y0 = (int)floorf(iny);
    int x0 = (int)floorf(inx);
    float fy = iny - (float)y0;
    float fx = inx - (float)x0;
    int y0c = max(y0, 0), y1c = min(y0 + 1, FH - 1);
    int x0c = max(x0, 0), x1c = min(x0 + 1, FW - 1);
    float v00 = row[y0c * FW + x0c];
    float v01 = row[y0c * FW + x1c];
    float v10 = row[y1c * FW + x0c];
    float v11 = row[y1c * FW + x1c];
    // H contracted first, then W (separate mul/add, no fma contraction)
    float vy0 = __fadd_rn(__fmul_rn(v00, 1.0f - fy), __fmul_rn(v10, fy));
    float vy1 = __fadd_rn(__fmul_rn(v01, 1.0f - fy), __fmul_rn(v11, fy));
    float val = __fadd_rn(__fmul_rn(vy0, 1.0f - fx), __fmul_rn(vy1, fx));
    bool m = val > 0.5f;
    out[200 + (size_t)f * OPIX + pix] = m ? 1.0f : 0.0f;

    // bbox reduce: within a wave, ox is lane-consecutive
    unsigned long long bal = __ballot(m);
    int lane = threadIdx.x & 63;
    int wv = threadIdx.x >> 6;
    __shared__ int wmin[4], wmax[4];
    if (lane == 0) {
        if (bal) {
            int bx = ox;  // lane 0's ox
            wmin[wv] = bx + (__ffsll((unsigned long long)bal) - 1);
            wmax[wv] = bx + (63 - __clzll((long long)bal));
        } else {
            wmin[wv] = 1 << 20;
            wmax[wv] = -1;
        }
    }
    __syncthreads();
    if (threadIdx.x == 0) {
        int mn = min(min(wmin[0], wmin[1]), min(wmin[2], wmin[3]));
        int mx = max(max(wmax[0], wmax[1]), max(wmax[2], wmax[3]));
        if (mx >= 0) {
            atomicMin(&boxes_i[f * 4 + 0], mn);
            atomicMin(&boxes_i[f * 4 + 1], oy);
            atomicMax(&boxes_i[f * 4 + 2], mx);
            atomicMax(&boxes_i[f * 4 + 3], oy);
        }
    }
}

// ---------------- boxes finalize ----------------
__global__ void k_boxes(const int* __restrict__ boxes_i, float* __restrict__ out) {
    int f = threadIdx.x;
    if (f < MAXI) {
        float sc = out[f];
        float mlt = (sc > 0.0f) ? 1.0f : 0.0f;
        size_t base = 200 + (size_t)MAXI * OPIX;
        out[base + f * 4 + 0] = (float)boxes_i[f * 4 + 0] * mlt;
        out[base + f * 4 + 1] = (float)boxes_i[f * 4 + 1] * mlt;
        out[base + f * 4 + 2] = (float)boxes_i[f * 4 + 2] * mlt;
        out[base + f * 4 + 3] = (float)boxes_i[f * 4 + 3] * mlt;
    }
}

extern "C" void kernel_launch(void* const* d_in, const int* in_sizes, int n_in,
                              void* d_out, int out_size, void* d_ws, size_t ws_size,
                              hipStream_t stream) {
    const float* cate = (const float*)d_in[0];
    const float* seg  = (const float*)d_in[1];
    float* out = (float*)d_out;
    char* ws = (char*)d_ws;

    unsigned* hist       = (unsigned*)(ws + OFF_HIST);
    unsigned* counters   = (unsigned*)(ws + OFF_CNT);
    unsigned long long* keybuf = (unsigned long long*)(ws + OFF_KEYBUF);
    int* e_gidx          = (int*)(ws + OFF_EGIDX);
    int* e_label         = (int*)(ws + OFF_ELABEL);
    int* e_count         = (int*)(ws + OFF_ECOUNT);
    float* tk_score      = (float*)(ws + OFF_TKSCORE);
    double* e_score1     = (double*)(ws + OFF_ESCORE1);
    int* order1          = (int*)(ws + OFF_ORDER1);
    double* score_s      = (double*)(ws + OFF_SCORES);
    float* comp          = (float*)(ws + OFF_COMP);
    double* eci          = (double*)(ws + OFF_ECI);
    double* ns           = (double*)(ws + OFF_NS);
    int* final_e         = (int*)(ws + OFF_FINALE);
    int* boxes_i         = (int*)(ws + OFF_BOXESI);
    unsigned long long* packed = (unsigned long long*)(ws + OFF_PACKED);
    float* dmat          = (float*)(ws + OFF_DMAT);

    hipLaunchKernelGGL(k_init, dim3(64), dim3(256), 0, stream, hist, counters, boxes_i);
    hipLaunchKernelGGL(k_hist, dim3(NFLAT / 256), dim3(256), 0, stream, cate, hist);
    hipLaunchKernelGGL(k_findB, dim3(1), dim3(1024), 0, stream, hist, counters);
    hipLaunchKernelGGL(k_collect, dim3(NFLAT / 256), dim3(256), 0, stream, cate, counters, keybuf);
    hipLaunchKernelGGL(k_sort_collect, dim3(1), dim3(1024), 0, stream, keybuf, counters, e_gidx, e_label, tk_score);
    hipLaunchKernelGGL(k_maskstats, dim3(PRE), dim3(256), 0, stream, seg, e_gidx, tk_score, packed, e_count, e_score1);
    hipLaunchKernelGGL(k_sort1, dim3(1), dim3(512), 0, stream, e_score1, order1, score_s);
    hipLaunchKernelGGL(k_dmat, dim3(32, 32), dim3(256), 0, stream, packed, order1, e_count, e_label, dmat);
    hipLaunchKernelGGL(k_comp, dim3(1), dim3(512), 0, stream, dmat, comp, eci);
    hipLaunchKernelGGL(k_coef, dim3(1), dim3(512), 0, stream, dmat, comp, eci, score_s, ns);
    hipLaunchKernelGGL(k_sort2, dim3(1), dim3(512), 0, stream, ns, order1, e_label, out, final_e);
    hipLaunchKernelGGL(k_upsample, dim3(OPIX / 256, MAXI), dim3(256), 0, stream, seg, final_e, e_gidx, out, boxes_i);
    hipLaunchKernelGGL(k_boxes, dim3(1), dim3(128), 0, stream, boxes_i, out);
}

// Round 2
// 872.211 us; speedup vs baseline: 3.1974x; 3.1974x over previous
//
#include <hip/hip_runtime.h>
#include <hip/hip_bf16.h>

// Problem constants
#define N_CELLS   3872
#define NCLS      80
#define NFLAT     309760        // 3872*80
#define FH        128
#define FW        192
#define HW        24576         // 128*192
#define WORDS     384           // HW/64
#define PRE       500
#define OH        512
#define OW        768
#define OPIX      393216        // 512*768
#define MAXI      100
#define NBUCKET   16384
#define COLCAP    4096

// Workspace byte offsets (all 8B aligned)
#define OFF_HIST      0          // u32[16384]
#define OFF_CNT       65536      // u32[16]   [0]=collect count, [1]=bucket B
#define OFF_KEYBUF    65600      // u64[4096]
#define OFF_EGIDX     98368      // i32[512]
#define OFF_ELABEL    100416     // i32[512]
#define OFF_ECOUNT    102464     // i32[512]
#define OFF_TKSCORE   104512     // f32[512]
#define OFF_ESCORE1   106560     // f64[512]
#define OFF_ORDER1    110656     // i32[512]
#define OFF_SCORES    112704     // f64[512]  sorted-1 scores
#define OFF_COMP      116800     // f32[512]
#define OFF_ECI       118848     // f64[512]  exp(comp^2/2)
#define OFF_NS        122944     // f64[512]  post-NMS scores (sorted-1 space)
#define OFF_FINALE    127040     // i32[128]
#define OFF_BOXESI    127552     // i32[400]
#define OFF_PACKED    129152     // u64[500*384]
#define OFF_DMAT      1665152    // f32[500*500]
// total ~2.67 MB

// upsample decomposition
#define UPS_BLOCKS        16
#define GROUPS_PER_F      98304   // OPIX/4
#define GROUPS_PER_BLOCK  6144    // GROUPS_PER_F / UPS_BLOCKS
#define UPS_ITERS         24      // GROUPS_PER_BLOCK / 256

__device__ __forceinline__ float stride_of(int g) {
    return (g < 2896) ? 8.0f : (g < 3472) ? 16.0f : 32.0f;
}

__device__ __forceinline__ int bucket_of(float v) {
    int b = (int)((v - 0.1f) * (16384.0f / 0.9f));
    return min(max(b, 0), NBUCKET - 1);
}

// ---------------- init ----------------
__global__ void k_init(unsigned* hist, unsigned* counters, int* boxes) {
    int i = blockIdx.x * blockDim.x + threadIdx.x;
    if (i < NBUCKET) hist[i] = 0u;
    if (i < 16) counters[i] = 0u;
    if (i < MAXI) {
        boxes[4*i+0] = OW;   // xmin sentinel
        boxes[4*i+1] = OH;   // ymin sentinel
        boxes[4*i+2] = 0;    // xmax sentinel
        boxes[4*i+3] = 0;    // ymax sentinel
    }
}

// ---------------- histogram of cate scores > 0.1 ----------------
__global__ void k_hist(const float* __restrict__ cate, unsigned* __restrict__ hist) {
    int i = blockIdx.x * blockDim.x + threadIdx.x;
    if (i >= NFLAT) return;
    float v = cate[i];
    if (v > 0.1f) atomicAdd(&hist[bucket_of(v)], 1u);
}

// ---------------- find bucket threshold B (top-500 live in buckets >= B) ----------------
__global__ __launch_bounds__(1024) void k_findB(const unsigned* __restrict__ hist, unsigned* counters) {
    __shared__ unsigned part[1024];
    int t = threadIdx.x;
    unsigned s = 0;
    for (int k = 0; k < 16; k++) s += hist[t * 16 + k];
    part[t] = s;
    __syncthreads();
    if (t == 0) {
        unsigned cum = 0;
        int B = 0;
        for (int c = 1023; c >= 0; c--) {
            if (cum + part[c] >= (unsigned)PRE) {
                unsigned cum2 = cum;
                int b = c * 16 + 15;
                for (; b >= c * 16; b--) {
                    cum2 += hist[b];
                    if (cum2 >= (unsigned)PRE) break;
                }
                B = (b < c * 16) ? c * 16 : b;
                counters[1] = (unsigned)B;
                return;
            }
            cum += part[c];
        }
        counters[1] = 0u;  // fewer than 500 candidates total
    }
}

// ---------------- collect candidates in buckets >= B ----------------
__global__ void k_collect(const float* __restrict__ cate, unsigned* counters,
                          unsigned long long* __restrict__ keybuf) {
    int i = blockIdx.x * blockDim.x + threadIdx.x;
    if (i >= NFLAT) return;
    float v = cate[i];
    if (v > 0.1f) {
        if (bucket_of(v) >= (int)counters[1]) {
            unsigned pos = atomicAdd(&counters[0], 1u);
            if (pos < COLCAP) {
                unsigned fb = __float_as_uint(v);
                keybuf[pos] = ((unsigned long long)fb << 32) | (unsigned long long)(0xFFFFFFFFu - (unsigned)i);
            }
        }
    }
}

// ---------------- sort collected (<=4096) desc, emit top-500 ----------------
__global__ __launch_bounds__(1024) void k_sort_collect(const unsigned long long* __restrict__ keybuf,
                                                       const unsigned* counters,
                                                       int* e_gidx, int* e_label, float* tk_score) {
    __shared__ unsigned long long k[COLCAP];
    int t = threadIdx.x;
    unsigned cnt = counters[0];
    if (cnt > COLCAP) cnt = COLCAP;
    for (int i = t; i < COLCAP; i += 1024) k[i] = (i < (int)cnt) ? keybuf[i] : 0ull;
    __syncthreads();
    for (int sz = 2; sz <= COLCAP; sz <<= 1) {
        for (int j = sz >> 1; j > 0; j >>= 1) {
            for (int i = t; i < COLCAP; i += 1024) {
                int ixj = i ^ j;
                if (ixj > i) {
                    bool up = ((i & sz) == 0);
                    unsigned long long a = k[i], b = k[ixj];
                    bool sw = up ? (a < b) : (a > b);   // descending
                    if (sw) { k[i] = b; k[ixj] = a; }
                }
            }
            __syncthreads();
        }
    }
    if (t < PRE) {
        unsigned long long key = k[t];
        if (key == 0ull) {  // defensive: fewer than 500 candidates
            e_gidx[t] = 0; e_label[t] = 0; tk_score[t] = -1.0f;
        } else {
            unsigned idx = 0xFFFFFFFFu - (unsigned)(key & 0xFFFFFFFFull);
            e_gidx[t] = (int)(idx / NCLS);
            e_label[t] = (int)(idx % NCLS);
            tk_score[t] = __uint_as_float((unsigned)(key >> 32));
        }
    }
}

// ---------------- per-candidate mask stats + bit-pack ----------------
__global__ __launch_bounds__(256) void k_maskstats(const float* __restrict__ seg,
                                                   const int* __restrict__ e_gidx,
                                                   const float* __restrict__ tk_score,
                                                   unsigned long long* __restrict__ packed,
                                                   int* __restrict__ e_count,
                                                   double* __restrict__ e_score1) {
    int e = blockIdx.x;
    const float* row = seg + (size_t)e_gidx[e] * HW;
    int t = threadIdx.x;
    int lane = t & 63;
    int wv = t >> 6;
    double lsum = 0.0;
    int lcnt = 0;
    for (int p = t; p < HW; p += 256) {
        float v = row[p];
        bool m = v > 0.5f;
        unsigned long long bal = __ballot(m);
        if (lane == 0) packed[(size_t)e * WORDS + (p >> 6)] = bal;
        if (m) { lsum += (double)v; lcnt++; }
    }
    for (int off = 32; off > 0; off >>= 1) {
        lsum += __shfl_down(lsum, off);
        lcnt += __shfl_down(lcnt, off);
    }
    __shared__ double ssum[4];
    __shared__ int scnt[4];
    if (lane == 0) { ssum[wv] = lsum; scnt[wv] = lcnt; }
    __syncthreads();
    if (t == 0) {
        double sum = ssum[0] + ssum[1] + ssum[2] + ssum[3];
        int cnt = scnt[0] + scnt[1] + scnt[2] + scnt[3];
        double segsc = sum / (double)max(cnt, 1);
        float sc = tk_score[e];
        bool keep = (sc > 0.1f) && ((float)cnt > stride_of(e_gidx[e]));
        e_count[e] = cnt;
        e_score1[e] = keep ? ((double)sc * segsc) : 0.0;
    }
}

// ---------------- stable descending sort of 500 doubles, emit permutation ----------------
__device__ __forceinline__ bool before_key(unsigned long long as, int ai,
                                           unsigned long long bs, int bi) {
    return (as > bs) || (as == bs && ai < bi);
}

__global__ __launch_bounds__(512) void k_sort1(const double* __restrict__ e_score1,
                                               int* __restrict__ order1,
                                               double* __restrict__ score_s) {
    __shared__ unsigned long long sb[512];
    __shared__ int si[512];
    int t = threadIdx.x;
    sb[t] = (t < PRE) ? (unsigned long long)__double_as_longlong(e_score1[t]) : 0ull;
    si[t] = t;
    __syncthreads();
    for (int sz = 2; sz <= 512; sz <<= 1) {
        for (int j = sz >> 1; j > 0; j >>= 1) {
            int ixj = t ^ j;
            if (ixj > t) {
                unsigned long long as = sb[t], bs = sb[ixj];
                int ai = si[t], bi = si[ixj];
                bool up = ((t & sz) == 0);
                bool aB = before_key(as, ai, bs, bi);
                bool sw = up ? (!aB) : aB;
                if (sw) { sb[t] = bs; sb[ixj] = as; si[t] = bi; si[ixj] = ai; }
            }
            __syncthreads();
        }
    }
    if (t < PRE) {
        order1[t] = si[t];
        score_s[t] = __longlong_as_double((long long)sb[t]);
    }
}

// ---------------- decay_iou matrix (upper triangle, same-label) ----------------
__global__ __launch_bounds__(256) void k_dmat(const unsigned long long* __restrict__ packed,
                                              const int* __restrict__ order1,
                                              const int* __restrict__ e_count,
                                              const int* __restrict__ e_label,
                                              float* __restrict__ dmat) {
    int bi = blockIdx.x, bj = blockIdx.y;
    int r = threadIdx.x >> 4, c = threadIdx.x & 15;
    int i = bi * 16 + r, j = bj * 16 + c;
    if (bi > bj) {  // whole tile is lower triangle -> zeros
        if (i < PRE && j < PRE) dmat[i * PRE + j] = 0.0f;
        return;
    }
    __shared__ unsigned long long A[16][65];
    __shared__ unsigned long long B[16][65];
    int oi = (i < PRE) ? order1[i] : -1;
    int oj = (j < PRE) ? order1[j] : -1;
    long long inter = 0;
    for (int ch = 0; ch < 6; ch++) {
        for (int l = threadIdx.x; l < 1024; l += 256) {
            int rr = l >> 6, ww = l & 63;
            int ii = bi * 16 + rr;
            int o = (ii < PRE) ? order1[ii] : -1;
            A[rr][ww] = (o >= 0) ? packed[(size_t)o * WORDS + ch * 64 + ww] : 0ull;
            int jj = bj * 16 + rr;
            int o2 = (jj < PRE) ? order1[jj] : -1;
            B[rr][ww] = (o2 >= 0) ? packed[(size_t)o2 * WORDS + ch * 64 + ww] : 0ull;
        }
        __syncthreads();
        #pragma unroll
        for (int w = 0; w < 64; w++) inter += __popcll(A[r][w] & B[c][w]);
        __syncthreads();
    }
    if (i < PRE && j < PRE) {
        float d = 0.0f;
        if (i < j && e_label[oi] == e_label[oj]) {
            double un = (double)(e_count[oi] + e_count[oj]) - (double)inter;
            double iou = (double)inter / fmax(un, 1e-6);
            d = (float)iou;
        }
        dmat[i * PRE + j] = d;
    }
}

// ---------------- compensate (column max) + exp(comp^2/2) ----------------
__global__ __launch_bounds__(64) void k_comp(const float* __restrict__ dmat,
                                             float* __restrict__ comp,
                                             double* __restrict__ eci) {
    int t = blockIdx.x * 64 + threadIdx.x;
    if (t < PRE) {
        float m = 0.0f;
        for (int i = 0; i < PRE; i++) m = fmaxf(m, dmat[i * PRE + t]);
        comp[t] = m;
        eci[t] = exp((double)m * (double)m * 0.5);
    }
}

// ---------------- coef (column min of decay) + score update ----------------
__global__ __launch_bounds__(64) void k_coef(const float* __restrict__ dmat,
                                             const float* __restrict__ comp,
                                             const double* __restrict__ eci,
                                             const double* __restrict__ score_s,
                                             double* __restrict__ ns) {
    int t = blockIdx.x * 64 + threadIdx.x;
    if (t < PRE) {
        double m = 1e300;
        for (int i = 0; i < PRE; i++) {
            float d = dmat[i * PRE + t];
            double v;
            if (d != 0.0f) {
                double dd = (double)d, cc = (double)comp[i];
                v = exp(-(dd * dd - cc * cc) * 0.5);
            } else {
                v = eci[i];
            }
            m = fmin(m, v);
        }
        double s = score_s[t] * m;
        if (s < 0.05) s = 0.0;
        ns[t] = s;
    }
}

// ---------------- final stable sort, emit scores/labels/final_e ----------------
__global__ __launch_bounds__(512) void k_sort2(const double* __restrict__ ns,
                                               const int* __restrict__ order1,
                                               const int* __restrict__ e_label,
                                               float* __restrict__ out,
                                               int* __restrict__ final_e) {
    __shared__ unsigned long long sb[512];
    __shared__ int si[512];
    int t = threadIdx.x;
    sb[t] = (t < PRE) ? (unsigned long long)__double_as_longlong(ns[t]) : 0ull;
    si[t] = t;
    __syncthreads();
    for (int sz = 2; sz <= 512; sz <<= 1) {
        for (int j = sz >> 1; j > 0; j >>= 1) {
            int ixj = t ^ j;
            if (ixj > t) {
                unsigned long long as = sb[t], bs = sb[ixj];
                int ai = si[t], bi = si[ixj];
                bool up = ((t & sz) == 0);
                bool aB = before_key(as, ai, bs, bi);
                bool sw = up ? (!aB) : aB;
                if (sw) { sb[t] = bs; sb[ixj] = as; si[t] = bi; si[ixj] = ai; }
            }
            __syncthreads();
        }
    }
    if (t < MAXI) {
        double s = __longlong_as_double((long long)sb[t]);
        int p = si[t];
        int e = order1[p];
        out[t] = (float)s;
        out[MAXI + t] = (float)e_label[e];
        final_e[t] = e;
    }
}

// ---------------- upsample 4x bilinear + threshold + bbox ----------------
// Grid: (UPS_BLOCKS, MAXI). Each thread computes a float4 of 4 consecutive
// output pixels (one 4-aligned x-group maps to 3 feature columns, 2 rows).
// Bbox is reduced per-block; only 4 atomics per block (64 per instance).
__global__ __launch_bounds__(256) void k_upsample(const float* __restrict__ seg,
                                                  const int* __restrict__ final_e,
                                                  const int* __restrict__ e_gidx,
                                                  float* __restrict__ out,
                                                  int* __restrict__ boxes_i) {
    int f = blockIdx.y;
    int e = final_e[f];
    const float* fm = seg + (size_t)e_gidx[e] * HW;
    float* obase = out + 200 + (size_t)f * OPIX;   // 800 B offset: 16B-aligned
    int xmin = 1 << 20, xmax = -1, ymin = 1 << 20, ymax = -1;
    int base = blockIdx.x * GROUPS_PER_BLOCK + threadIdx.x;
    #pragma unroll 4
    for (int k = 0; k < UPS_ITERS; k++) {
        int p = base + k * 256;
        int oy = p / (OW / 4);
        int gx = p - oy * (OW / 4);
        float iny = (float)oy * 0.25f - 0.375f;
        int y0 = (int)floorf(iny);
        float fy = iny - (float)y0;
        int y0c = max(y0, 0), y1c = min(y0 + 1, FH - 1);
        int xm = max(gx - 1, 0), xp = min(gx + 1, FW - 1);
        const float* r0 = fm + y0c * FW;
        const float* r1 = fm + y1c * FW;
        float am = r0[xm], a0 = r0[gx], ap = r0[xp];
        float bm = r1[xm], b0 = r1[gx], bp = r1[xp];
        float gy = 1.0f - fy;
        // vertical lerp first (matches reference H-then-W order), no fma contraction
        float vm = __fadd_rn(__fmul_rn(am, gy), __fmul_rn(bm, fy));
        float v0 = __fadd_rn(__fmul_rn(a0, gy), __fmul_rn(b0, fy));
        float vp = __fadd_rn(__fmul_rn(ap, gy), __fmul_rn(bp, fy));
        // horizontal: fx per sub-pixel = {0.625, 0.875, 0.125, 0.375}
        float o0 = __fadd_rn(__fmul_rn(vm, 0.375f), __fmul_rn(v0, 0.625f));
        float o1 = __fadd_rn(__fmul_rn(vm, 0.125f), __fmul_rn(v0, 0.875f));
        float o2 = __fadd_rn(__fmul_rn(v0, 0.875f), __fmul_rn(vp, 0.125f));
        float o3 = __fadd_rn(__fmul_rn(v0, 0.625f), __fmul_rn(vp, 0.375f));
        bool m0 = o0 > 0.5f, m1 = o1 > 0.5f, m2 = o2 > 0.5f, m3 = o3 > 0.5f;
        float4 w;
        w.x = m0 ? 1.0f : 0.0f;
        w.y = m1 ? 1.0f : 0.0f;
        w.z = m2 ? 1.0f : 0.0f;
        w.w = m3 ? 1.0f : 0.0f;
        *(float4*)(obase + (size_t)p * 4) = w;
        if (m0 | m1 | m2 | m3) {
            int ox0 = gx * 4;
            ymin = min(ymin, oy);
            ymax = max(ymax, oy);
            int lo = m0 ? 0 : (m1 ? 1 : (m2 ? 2 : 3));
            int hi = m3 ? 3 : (m2 ? 2 : (m1 ? 1 : 0));
            xmin = min(xmin, ox0 + lo);
            xmax = max(xmax, ox0 + hi);
        }
    }
    // wave reduce
    for (int off = 32; off > 0; off >>= 1) {
        xmin = min(xmin, __shfl_down(xmin, off));
        xmax = max(xmax, __shfl_down(xmax, off));
        ymin = min(ymin, __shfl_down(ymin, off));
        ymax = max(ymax, __shfl_down(ymax, off));
    }
    __shared__ int sxm[4], sxM[4], sym[4], syM[4];
    int lane = threadIdx.x & 63, wv = threadIdx.x >> 6;
    if (lane == 0) { sxm[wv] = xmin; sxM[wv] = xmax; sym[wv] = ymin; syM[wv] = ymax; }
    __syncthreads();
    if (threadIdx.x == 0) {
        int mnx = min(min(sxm[0], sxm[1]), min(sxm[2], sxm[3]));
        int mxx = max(max(sxM[0], sxM[1]), max(sxM[2], sxM[3]));
        int mny = min(min(sym[0], sym[1]), min(sym[2], sym[3]));
        int mxy = max(max(syM[0], syM[1]), max(syM[2], syM[3]));
        if (mxx >= 0) {
            atomicMin(&boxes_i[f * 4 + 0], mnx);
            atomicMin(&boxes_i[f * 4 + 1], mny);
            atomicMax(&boxes_i[f * 4 + 2], mxx);
            atomicMax(&boxes_i[f * 4 + 3], mxy);
        }
    }
}

// ---------------- boxes finalize ----------------
__global__ void k_boxes(const int* __restrict__ boxes_i, float* __restrict__ out) {
    int f = threadIdx.x;
    if (f < MAXI) {
        float sc = out[f];
        float mlt = (sc > 0.0f) ? 1.0f : 0.0f;
        size_t base = 200 + (size_t)MAXI * OPIX;
        out[base + f * 4 + 0] = (float)boxes_i[f * 4 + 0] * mlt;
        out[base + f * 4 + 1] = (float)boxes_i[f * 4 + 1] * mlt;
        out[base + f * 4 + 2] = (float)boxes_i[f * 4 + 2] * mlt;
        out[base + f * 4 + 3] = (float)boxes_i[f * 4 + 3] * mlt;
    }
}

extern "C" void kernel_launch(void* const* d_in, const int* in_sizes, int n_in,
                              void* d_out, int out_size, void* d_ws, size_t ws_size,
                              hipStream_t stream) {
    const float* cate = (const float*)d_in[0];
    const float* seg  = (const float*)d_in[1];
    float* out = (float*)d_out;
    char* ws = (char*)d_ws;

    unsigned* hist       = (unsigned*)(ws + OFF_HIST);
    unsigned* counters   = (unsigned*)(ws + OFF_CNT);
    unsigned long long* keybuf = (unsigned long long*)(ws + OFF_KEYBUF);
    int* e_gidx          = (int*)(ws + OFF_EGIDX);
    int* e_label         = (int*)(ws + OFF_ELABEL);
    int* e_count         = (int*)(ws + OFF_ECOUNT);
    float* tk_score      = (float*)(ws + OFF_TKSCORE);
    double* e_score1     = (double*)(ws + OFF_ESCORE1);
    int* order1          = (int*)(ws + OFF_ORDER1);
    double* score_s      = (double*)(ws + OFF_SCORES);
    float* comp          = (float*)(ws + OFF_COMP);
    double* eci          = (double*)(ws + OFF_ECI);
    double* ns           = (double*)(ws + OFF_NS);
    int* final_e         = (int*)(ws + OFF_FINALE);
    int* boxes_i         = (int*)(ws + OFF_BOXESI);
    unsigned long long* packed = (unsigned long long*)(ws + OFF_PACKED);
    float* dmat          = (float*)(ws + OFF_DMAT);

    hipLaunchKernelGGL(k_init, dim3(64), dim3(256), 0, stream, hist, counters, boxes_i);
    hipLaunchKernelGGL(k_hist, dim3(NFLAT / 256), dim3(256), 0, stream, cate, hist);
    hipLaunchKernelGGL(k_findB, dim3(1), dim3(1024), 0, stream, hist, counters);
    hipLaunchKernelGGL(k_collect, dim3(NFLAT / 256), dim3(256), 0, stream, cate, counters, keybuf);
    hipLaunchKernelGGL(k_sort_collect, dim3(1), dim3(1024), 0, stream, keybuf, counters, e_gidx, e_label, tk_score);
    hipLaunchKernelGGL(k_maskstats, dim3(PRE), dim3(256), 0, stream, seg, e_gidx, tk_score, packed, e_count, e_score1);
    hipLaunchKernelGGL(k_sort1, dim3(1), dim3(512), 0, stream, e_score1, order1, score_s);
    hipLaunchKernelGGL(k_dmat, dim3(32, 32), dim3(256), 0, stream, packed, order1, e_count, e_label, dmat);
    hipLaunchKernelGGL(k_comp, dim3(8), dim3(64), 0, stream, dmat, comp, eci);
    hipLaunchKernelGGL(k_coef, dim3(8), dim3(64), 0, stream, dmat, comp, eci, score_s, ns);
    hipLaunchKernelGGL(k_sort2, dim3(1), dim3(512), 0, stream, ns, order1, e_label, out, final_e);
    hipLaunchKernelGGL(k_upsample, dim3(UPS_BLOCKS, MAXI), dim3(256), 0, stream, seg, final_e, e_gidx, out, boxes_i);
    hipLaunchKernelGGL(k_boxes, dim3(1), dim3(128), 0, stream, boxes_i, out);
}

// Round 3
// 791.865 us; speedup vs baseline: 3.5218x; 1.1015x over previous
//
#include <hip/hip_runtime.h>
#include <hip/hip_bf16.h>

// Problem constants
#define N_CELLS   3872
#define NCLS      80
#define NFLAT     309760        // 3872*80
#define FH        128
#define FW        192
#define HW        24576         // 128*192
#define WORDS     384           // HW/64
#define PRE       500
#define OH        512
#define OW        768
#define OPIX      393216        // 512*768
#define MAXI      100
#define NBUCKET   16384
#define COLCAP    4096

// Workspace byte offsets (all 8B aligned)
#define OFF_HIST      0          // u32[16384]
#define OFF_CNT       65536      // u32[16]   [0]=collect count, [1]=bucket B
#define OFF_KEYBUF    65600      // u64[4096]
#define OFF_EGIDX     98368      // i32[512]
#define OFF_ELABEL    100416     // i32[512]
#define OFF_ECOUNT    102464     // i32[512]
#define OFF_TKSCORE   104512     // f32[512]
#define OFF_ESCORE1   106560     // f64[512]
#define OFF_ORDER1    110656     // i32[512]
#define OFF_SCORES    112704     // f64[512]  sorted-1 scores
#define OFF_COMP      116800     // f32[512]
#define OFF_ECI       118848     // f64[512]  exp(comp^2/2)
#define OFF_NS        122944     // f64[512]  post-NMS scores (sorted-1 space)
#define OFF_FINALE    127040     // i32[128]
#define OFF_BOXESI    127552     // i32[400]
#define OFF_PACKED    129152     // u64[500*384]
#define OFF_DMAT      1665152    // f32[500*500]
// total ~2.67 MB

// upsample decomposition
#define UPS_BLOCKS        24
#define GROUPS_PER_F      98304   // OPIX/4
#define GROUPS_PER_BLOCK  4096    // GROUPS_PER_F / UPS_BLOCKS
#define UPS_ITERS         16      // GROUPS_PER_BLOCK / 256

__device__ __forceinline__ float stride_of(int g) {
    return (g < 2896) ? 8.0f : (g < 3472) ? 16.0f : 32.0f;
}

__device__ __forceinline__ int bucket_of(float v) {
    int b = (int)((v - 0.1f) * (16384.0f / 0.9f));
    return min(max(b, 0), NBUCKET - 1);
}

// deposit 16 low bits of x to every 4th bit position of a u64
__device__ __forceinline__ unsigned long long spread4(unsigned x) {
    unsigned long long v = (unsigned long long)(x & 0xFFFFu);
    v = (v | (v << 24)) & 0x000000FF000000FFull;
    v = (v | (v << 12)) & 0x000F000F000F000Full;
    v = (v | (v << 6))  & 0x0303030303030303ull;
    v = (v | (v << 3))  & 0x1111111111111111ull;
    return v;
}

// ---------------- init ----------------
__global__ void k_init(unsigned* hist, unsigned* counters, int* boxes) {
    int i = blockIdx.x * blockDim.x + threadIdx.x;
    if (i < NBUCKET) hist[i] = 0u;
    if (i < 16) counters[i] = 0u;
    if (i < MAXI) {
        boxes[4*i+0] = OW;   // xmin sentinel
        boxes[4*i+1] = OH;   // ymin sentinel
        boxes[4*i+2] = 0;    // xmax sentinel
        boxes[4*i+3] = 0;    // ymax sentinel
    }
}

// ---------------- histogram of cate scores > 0.1 (float4) ----------------
__global__ void k_hist(const float4* __restrict__ cate4, unsigned* __restrict__ hist) {
    int i = blockIdx.x * blockDim.x + threadIdx.x;
    if (i >= NFLAT / 4) return;
    float4 v = cate4[i];
    if (v.x > 0.1f) atomicAdd(&hist[bucket_of(v.x)], 1u);
    if (v.y > 0.1f) atomicAdd(&hist[bucket_of(v.y)], 1u);
    if (v.z > 0.1f) atomicAdd(&hist[bucket_of(v.z)], 1u);
    if (v.w > 0.1f) atomicAdd(&hist[bucket_of(v.w)], 1u);
}

// ---------------- find bucket threshold B (top-500 live in buckets >= B) ----------------
__global__ __launch_bounds__(1024) void k_findB(const unsigned* __restrict__ hist, unsigned* counters) {
    __shared__ unsigned part[1024];
    int t = threadIdx.x;
    unsigned s = 0;
    for (int k = 0; k < 16; k++) s += hist[t * 16 + k];
    part[t] = s;
    __syncthreads();
    if (t == 0) {
        unsigned cum = 0;
        int B = 0;
        for (int c = 1023; c >= 0; c--) {
            if (cum + part[c] >= (unsigned)PRE) {
                unsigned cum2 = cum;
                int b = c * 16 + 15;
                for (; b >= c * 16; b--) {
                    cum2 += hist[b];
                    if (cum2 >= (unsigned)PRE) break;
                }
                B = (b < c * 16) ? c * 16 : b;
                counters[1] = (unsigned)B;
                return;
            }
            cum += part[c];
        }
        counters[1] = 0u;  // fewer than 500 candidates total
    }
}

// ---------------- collect candidates in buckets >= B (float4) ----------------
__global__ void k_collect(const float4* __restrict__ cate4, unsigned* counters,
                          unsigned long long* __restrict__ keybuf) {
    int i = blockIdx.x * blockDim.x + threadIdx.x;
    if (i >= NFLAT / 4) return;
    float4 v = cate4[i];
    int B = (int)counters[1];
    int base = 4 * i;
    float vv[4] = {v.x, v.y, v.z, v.w};
    #pragma unroll
    for (int c = 0; c < 4; c++) {
        float f = vv[c];
        if (f > 0.1f && bucket_of(f) >= B) {
            unsigned pos = atomicAdd(&counters[0], 1u);
            if (pos < COLCAP) {
                unsigned fb = __float_as_uint(f);
                unsigned idx = (unsigned)(base + c);
                keybuf[pos] = ((unsigned long long)fb << 32) | (unsigned long long)(0xFFFFFFFFu - idx);
            }
        }
    }
}

// ---------------- sort collected (dynamic pow2 size) desc, emit top-500 ----------------
__global__ __launch_bounds__(1024) void k_sort_collect(const unsigned long long* __restrict__ keybuf,
                                                       const unsigned* counters,
                                                       int* e_gidx, int* e_label, float* tk_score) {
    __shared__ unsigned long long k[COLCAP];
    int t = threadIdx.x;
    unsigned cnt = counters[0];
    if (cnt > COLCAP) cnt = COLCAP;
    int m = 512;
    while (m < (int)cnt) m <<= 1;   // next pow2 >= cnt, min 512
    for (int i = t; i < m; i += 1024) k[i] = (i < (int)cnt) ? keybuf[i] : 0ull;
    __syncthreads();
    for (int sz = 2; sz <= m; sz <<= 1) {
        for (int j = sz >> 1; j > 0; j >>= 1) {
            for (int i = t; i < m; i += 1024) {
                int ixj = i ^ j;
                if (ixj > i) {
                    bool up = ((i & sz) == 0);
                    unsigned long long a = k[i], b = k[ixj];
                    bool sw = up ? (a < b) : (a > b);   // descending
                    if (sw) { k[i] = b; k[ixj] = a; }
                }
            }
            __syncthreads();
        }
    }
    if (t < PRE) {
        unsigned long long key = k[t];
        if (key == 0ull) {  // defensive: fewer than 500 candidates
            e_gidx[t] = 0; e_label[t] = 0; tk_score[t] = -1.0f;
        } else {
            unsigned idx = 0xFFFFFFFFu - (unsigned)(key & 0xFFFFFFFFull);
            e_gidx[t] = (int)(idx / NCLS);
            e_label[t] = (int)(idx % NCLS);
            tk_score[t] = __uint_as_float((unsigned)(key >> 32));
        }
    }
}

// ---------------- per-candidate mask stats + bit-pack (float4 loads) ----------------
__global__ __launch_bounds__(256) void k_maskstats(const float* __restrict__ seg,
                                                   const int* __restrict__ e_gidx,
                                                   const float* __restrict__ tk_score,
                                                   unsigned long long* __restrict__ packed,
                                                   int* __restrict__ e_count,
                                                   double* __restrict__ e_score1) {
    int e = blockIdx.x;
    const float4* row4 = (const float4*)(seg + (size_t)e_gidx[e] * HW);
    int t = threadIdx.x;
    int lane = t & 63;
    int wv = t >> 6;
    int w = lane >> 4;     // which of the wave's 4 words this lane helps assemble
    int sh = 16 * w;
    double lsum = 0.0;
    int lcnt = 0;
    #pragma unroll 4
    for (int k = 0; k < 24; k++) {
        int p4 = t + k * 256;          // float4 index; wave covers 256 consecutive pixels
        float4 v = row4[p4];
        unsigned nib = (v.x > 0.5f ? 1u : 0u) | (v.y > 0.5f ? 2u : 0u) |
                       (v.z > 0.5f ? 4u : 0u) | (v.w > 0.5f ? 8u : 0u);
        unsigned long long b0 = __ballot(nib & 1u);
        unsigned long long b1 = __ballot(nib & 2u);
        unsigned long long b2 = __ballot(nib & 4u);
        unsigned long long b3 = __ballot(nib & 8u);
        unsigned long long word = spread4((unsigned)(b0 >> sh))
                                | (spread4((unsigned)(b1 >> sh)) << 1)
                                | (spread4((unsigned)(b2 >> sh)) << 2)
                                | (spread4((unsigned)(b3 >> sh)) << 3);
        if ((lane & 15) == 0) packed[(size_t)e * WORDS + (k * 16 + wv * 4 + w)] = word;
        if (v.x > 0.5f) lsum += (double)v.x;
        if (v.y > 0.5f) lsum += (double)v.y;
        if (v.z > 0.5f) lsum += (double)v.z;
        if (v.w > 0.5f) lsum += (double)v.w;
        lcnt += __popc(nib);
    }
    for (int off = 32; off > 0; off >>= 1) {
        lsum += __shfl_down(lsum, off);
        lcnt += __shfl_down(lcnt, off);
    }
    __shared__ double ssum[4];
    __shared__ int scnt[4];
    if (lane == 0) { ssum[wv] = lsum; scnt[wv] = lcnt; }
    __syncthreads();
    if (t == 0) {
        double sum = ssum[0] + ssum[1] + ssum[2] + ssum[3];
        int cnt = scnt[0] + scnt[1] + scnt[2] + scnt[3];
        double segsc = sum / (double)max(cnt, 1);
        float sc = tk_score[e];
        bool keep = (sc > 0.1f) && ((float)cnt > stride_of(e_gidx[e]));
        e_count[e] = cnt;
        e_score1[e] = keep ? ((double)sc * segsc) : 0.0;
    }
}

// ---------------- stable descending sort of 500 doubles, emit permutation ----------------
__device__ __forceinline__ bool before_key(unsigned long long as, int ai,
                                           unsigned long long bs, int bi) {
    return (as > bs) || (as == bs && ai < bi);
}

__global__ __launch_bounds__(512) void k_sort1(const double* __restrict__ e_score1,
                                               int* __restrict__ order1,
                                               double* __restrict__ score_s) {
    __shared__ unsigned long long sb[512];
    __shared__ int si[512];
    int t = threadIdx.x;
    sb[t] = (t < PRE) ? (unsigned long long)__double_as_longlong(e_score1[t]) : 0ull;
    si[t] = t;
    __syncthreads();
    for (int sz = 2; sz <= 512; sz <<= 1) {
        for (int j = sz >> 1; j > 0; j >>= 1) {
            int ixj = t ^ j;
            if (ixj > t) {
                unsigned long long as = sb[t], bs = sb[ixj];
                int ai = si[t], bi = si[ixj];
                bool up = ((t & sz) == 0);
                bool aB = before_key(as, ai, bs, bi);
                bool sw = up ? (!aB) : aB;
                if (sw) { sb[t] = bs; sb[ixj] = as; si[t] = bi; si[ixj] = ai; }
            }
            __syncthreads();
        }
    }
    if (t < PRE) {
        order1[t] = si[t];
        score_s[t] = __longlong_as_double((long long)sb[t]);
    }
}

// ---------------- decay_iou matrix (upper triangle, same-label) ----------------
__global__ __launch_bounds__(256) void k_dmat(const unsigned long long* __restrict__ packed,
                                              const int* __restrict__ order1,
                                              const int* __restrict__ e_count,
                                              const int* __restrict__ e_label,
                                              float* __restrict__ dmat) {
    int bi = blockIdx.x, bj = blockIdx.y;
    int r = threadIdx.x >> 4, c = threadIdx.x & 15;
    int i = bi * 16 + r, j = bj * 16 + c;
    if (bi > bj) {  // whole tile is lower triangle -> zeros
        if (i < PRE && j < PRE) dmat[i * PRE + j] = 0.0f;
        return;
    }
    __shared__ unsigned long long A[16][65];
    __shared__ unsigned long long B[16][65];
    int oi = (i < PRE) ? order1[i] : -1;
    int oj = (j < PRE) ? order1[j] : -1;
    long long inter = 0;
    for (int ch = 0; ch < 6; ch++) {
        for (int l = threadIdx.x; l < 1024; l += 256) {
            int rr = l >> 6, ww = l & 63;
            int ii = bi * 16 + rr;
            int o = (ii < PRE) ? order1[ii] : -1;
            A[rr][ww] = (o >= 0) ? packed[(size_t)o * WORDS + ch * 64 + ww] : 0ull;
            int jj = bj * 16 + rr;
            int o2 = (jj < PRE) ? order1[jj] : -1;
            B[rr][ww] = (o2 >= 0) ? packed[(size_t)o2 * WORDS + ch * 64 + ww] : 0ull;
        }
        __syncthreads();
        #pragma unroll
        for (int w = 0; w < 64; w++) inter += __popcll(A[r][w] & B[c][w]);
        __syncthreads();
    }
    if (i < PRE && j < PRE) {
        float d = 0.0f;
        if (i < j && e_label[oi] == e_label[oj]) {
            double un = (double)(e_count[oi] + e_count[oj]) - (double)inter;
            double iou = (double)inter / fmax(un, 1e-6);
            d = (float)iou;
        }
        dmat[i * PRE + j] = d;
    }
}

// ---------------- compensate (column max) + exp(comp^2/2) ----------------
__global__ __launch_bounds__(64) void k_comp(const float* __restrict__ dmat,
                                             float* __restrict__ comp,
                                             double* __restrict__ eci) {
    int t = blockIdx.x * 64 + threadIdx.x;
    if (t < PRE) {
        float m = 0.0f;
        for (int i = 0; i < PRE; i++) m = fmaxf(m, dmat[i * PRE + t]);
        comp[t] = m;
        eci[t] = exp((double)m * (double)m * 0.5);
    }
}

// ---------------- coef (column min of decay) + score update ----------------
__global__ __launch_bounds__(64) void k_coef(const float* __restrict__ dmat,
                                             const float* __restrict__ comp,
                                             const double* __restrict__ eci,
                                             const double* __restrict__ score_s,
                                             double* __restrict__ ns) {
    int t = blockIdx.x * 64 + threadIdx.x;
    if (t < PRE) {
        double m = 1e300;
        for (int i = 0; i < PRE; i++) {
            float d = dmat[i * PRE + t];
            double v;
            if (d != 0.0f) {
                double dd = (double)d, cc = (double)comp[i];
                v = exp(-(dd * dd - cc * cc) * 0.5);
            } else {
                v = eci[i];
            }
            m = fmin(m, v);
        }
        double s = score_s[t] * m;
        if (s < 0.05) s = 0.0;
        ns[t] = s;
    }
}

// ---------------- final stable sort, emit scores/labels/final_e ----------------
__global__ __launch_bounds__(512) void k_sort2(const double* __restrict__ ns,
                                               const int* __restrict__ order1,
                                               const int* __restrict__ e_label,
                                               float* __restrict__ out,
                                               int* __restrict__ final_e) {
    __shared__ unsigned long long sb[512];
    __shared__ int si[512];
    int t = threadIdx.x;
    sb[t] = (t < PRE) ? (unsigned long long)__double_as_longlong(ns[t]) : 0ull;
    si[t] = t;
    __syncthreads();
    for (int sz = 2; sz <= 512; sz <<= 1) {
        for (int j = sz >> 1; j > 0; j >>= 1) {
            int ixj = t ^ j;
            if (ixj > t) {
                unsigned long long as = sb[t], bs = sb[ixj];
                int ai = si[t], bi = si[ixj];
                bool up = ((t & sz) == 0);
                bool aB = before_key(as, ai, bs, bi);
                bool sw = up ? (!aB) : aB;
                if (sw) { sb[t] = bs; sb[ixj] = as; si[t] = bi; si[ixj] = ai; }
            }
            __syncthreads();
        }
    }
    if (t < MAXI) {
        double s = __longlong_as_double((long long)sb[t]);
        int p = si[t];
        int e = order1[p];
        out[t] = (float)s;
        out[MAXI + t] = (float)e_label[e];
        final_e[t] = e;
    }
}

// ---------------- upsample 4x bilinear + threshold + bbox ----------------
// Grid: (UPS_BLOCKS, MAXI). Each thread computes a float4 of 4 consecutive
// output pixels (one 4-aligned x-group maps to 3 feature columns, 2 rows).
// Bbox reduced per-block; 4 atomics per block.
__global__ __launch_bounds__(256) void k_upsample(const float* __restrict__ seg,
                                                  const int* __restrict__ final_e,
                                                  const int* __restrict__ e_gidx,
                                                  float* __restrict__ out,
                                                  int* __restrict__ boxes_i) {
    int f = blockIdx.y;
    int e = final_e[f];
    const float* fm = seg + (size_t)e_gidx[e] * HW;
    float* obase = out + 200 + (size_t)f * OPIX;   // 800 B offset: 16B-aligned
    int xmin = 1 << 20, xmax = -1, ymin = 1 << 20, ymax = -1;
    int base = blockIdx.x * GROUPS_PER_BLOCK + threadIdx.x;
    #pragma unroll 4
    for (int k = 0; k < UPS_ITERS; k++) {
        int p = base + k * 256;
        int oy = p / (OW / 4);
        int gx = p - oy * (OW / 4);
        float iny = (float)oy * 0.25f - 0.375f;
        int y0 = (int)floorf(iny);
        float fy = iny - (float)y0;
        int y0c = max(y0, 0), y1c = min(y0 + 1, FH - 1);
        int xm = max(gx - 1, 0), xp = min(gx + 1, FW - 1);
        const float* r0 = fm + y0c * FW;
        const float* r1 = fm + y1c * FW;
        float am = r0[xm], a0 = r0[gx], ap = r0[xp];
        float bm = r1[xm], b0 = r1[gx], bp = r1[xp];
        float gy = 1.0f - fy;
        // vertical lerp first (matches reference H-then-W order), no fma contraction
        float vm = __fadd_rn(__fmul_rn(am, gy), __fmul_rn(bm, fy));
        float v0 = __fadd_rn(__fmul_rn(a0, gy), __fmul_rn(b0, fy));
        float vp = __fadd_rn(__fmul_rn(ap, gy), __fmul_rn(bp, fy));
        // horizontal: fx per sub-pixel = {0.625, 0.875, 0.125, 0.375}
        float o0 = __fadd_rn(__fmul_rn(vm, 0.375f), __fmul_rn(v0, 0.625f));
        float o1 = __fadd_rn(__fmul_rn(vm, 0.125f), __fmul_rn(v0, 0.875f));
        float o2 = __fadd_rn(__fmul_rn(v0, 0.875f), __fmul_rn(vp, 0.125f));
        float o3 = __fadd_rn(__fmul_rn(v0, 0.625f), __fmul_rn(vp, 0.375f));
        bool m0 = o0 > 0.5f, m1 = o1 > 0.5f, m2 = o2 > 0.5f, m3 = o3 > 0.5f;
        float4 w;
        w.x = m0 ? 1.0f : 0.0f;
        w.y = m1 ? 1.0f : 0.0f;
        w.z = m2 ? 1.0f : 0.0f;
        w.w = m3 ? 1.0f : 0.0f;
        *(float4*)(obase + (size_t)p * 4) = w;
        if (m0 | m1 | m2 | m3) {
            int ox0 = gx * 4;
            ymin = min(ymin, oy);
            ymax = max(ymax, oy);
            int lo = m0 ? 0 : (m1 ? 1 : (m2 ? 2 : 3));
            int hi = m3 ? 3 : (m2 ? 2 : (m1 ? 1 : 0));
            xmin = min(xmin, ox0 + lo);
            xmax = max(xmax, ox0 + hi);
        }
    }
    // wave reduce
    for (int off = 32; off > 0; off >>= 1) {
        xmin = min(xmin, __shfl_down(xmin, off));
        xmax = max(xmax, __shfl_down(xmax, off));
        ymin = min(ymin, __shfl_down(ymin, off));
        ymax = max(ymax, __shfl_down(ymax, off));
    }
    __shared__ int sxm[4], sxM[4], sym[4], syM[4];
    int lane = threadIdx.x & 63, wv = threadIdx.x >> 6;
    if (lane == 0) { sxm[wv] = xmin; sxM[wv] = xmax; sym[wv] = ymin; syM[wv] = ymax; }
    __syncthreads();
    if (threadIdx.x == 0) {
        int mnx = min(min(sxm[0], sxm[1]), min(sxm[2], sxm[3]));
        int mxx = max(max(sxM[0], sxM[1]), max(sxM[2], sxM[3]));
        int mny = min(min(sym[0], sym[1]), min(sym[2], sym[3]));
        int mxy = max(max(syM[0], syM[1]), max(syM[2], syM[3]));
        if (mxx >= 0) {
            atomicMin(&boxes_i[f * 4 + 0], mnx);
            atomicMin(&boxes_i[f * 4 + 1], mny);
            atomicMax(&boxes_i[f * 4 + 2], mxx);
            atomicMax(&boxes_i[f * 4 + 3], mxy);
        }
    }
}

// ---------------- boxes finalize ----------------
__global__ void k_boxes(const int* __restrict__ boxes_i, float* __restrict__ out) {
    int f = threadIdx.x;
    if (f < MAXI) {
        float sc = out[f];
        float mlt = (sc > 0.0f) ? 1.0f : 0.0f;
        size_t base = 200 + (size_t)MAXI * OPIX;
        out[base + f * 4 + 0] = (float)boxes_i[f * 4 + 0] * mlt;
        out[base + f * 4 + 1] = (float)boxes_i[f * 4 + 1] * mlt;
        out[base + f * 4 + 2] = (float)boxes_i[f * 4 + 2] * mlt;
        out[base + f * 4 + 3] = (float)boxes_i[f * 4 + 3] * mlt;
    }
}

extern "C" void kernel_launch(void* const* d_in, const int* in_sizes, int n_in,
                              void* d_out, int out_size, void* d_ws, size_t ws_size,
                              hipStream_t stream) {
    const float* cate = (const float*)d_in[0];
    const float* seg  = (const float*)d_in[1];
    float* out = (float*)d_out;
    char* ws = (char*)d_ws;

    unsigned* hist       = (unsigned*)(ws + OFF_HIST);
    unsigned* counters   = (unsigned*)(ws + OFF_CNT);
    unsigned long long* keybuf = (unsigned long long*)(ws + OFF_KEYBUF);
    int* e_gidx          = (int*)(ws + OFF_EGIDX);
    int* e_label         = (int*)(ws + OFF_ELABEL);
    int* e_count         = (int*)(ws + OFF_ECOUNT);
    float* tk_score      = (float*)(ws + OFF_TKSCORE);
    double* e_score1     = (double*)(ws + OFF_ESCORE1);
    int* order1          = (int*)(ws + OFF_ORDER1);
    double* score_s      = (double*)(ws + OFF_SCORES);
    float* comp          = (float*)(ws + OFF_COMP);
    double* eci          = (double*)(ws + OFF_ECI);
    double* ns           = (double*)(ws + OFF_NS);
    int* final_e         = (int*)(ws + OFF_FINALE);
    int* boxes_i         = (int*)(ws + OFF_BOXESI);
    unsigned long long* packed = (unsigned long long*)(ws + OFF_PACKED);
    float* dmat          = (float*)(ws + OFF_DMAT);

    hipLaunchKernelGGL(k_init, dim3(64), dim3(256), 0, stream, hist, counters, boxes_i);
    hipLaunchKernelGGL(k_hist, dim3((NFLAT / 4 + 255) / 256), dim3(256), 0, stream,
                       (const float4*)cate, hist);
    hipLaunchKernelGGL(k_findB, dim3(1), dim3(1024), 0, stream, hist, counters);
    hipLaunchKernelGGL(k_collect, dim3((NFLAT / 4 + 255) / 256), dim3(256), 0, stream,
                       (const float4*)cate, counters, keybuf);
    hipLaunchKernelGGL(k_sort_collect, dim3(1), dim3(1024), 0, stream, keybuf, counters, e_gidx, e_label, tk_score);
    hipLaunchKernelGGL(k_maskstats, dim3(PRE), dim3(256), 0, stream, seg, e_gidx, tk_score, packed, e_count, e_score1);
    hipLaunchKernelGGL(k_sort1, dim3(1), dim3(512), 0, stream, e_score1, order1, score_s);
    hipLaunchKernelGGL(k_dmat, dim3(32, 32), dim3(256), 0, stream, packed, order1, e_count, e_label, dmat);
    hipLaunchKernelGGL(k_comp, dim3(8), dim3(64), 0, stream, dmat, comp, eci);
    hipLaunchKernelGGL(k_coef, dim3(8), dim3(64), 0, stream, dmat, comp, eci, score_s, ns);
    hipLaunchKernelGGL(k_sort2, dim3(1), dim3(512), 0, stream, ns, order1, e_label, out, final_e);
    hipLaunchKernelGGL(k_upsample, dim3(UPS_BLOCKS, MAXI), dim3(256), 0, stream, seg, final_e, e_gidx, out, boxes_i);
    hipLaunchKernelGGL(k_boxes, dim3(1), dim3(128), 0, stream, boxes_i, out);
}